// Round 3
// baseline (116.673 us; speedup 1.0000x reference)
//
#include <hip/hip_runtime.h>
#include <hip/hip_bf16.h>

typedef __attribute__((ext_vector_type(4))) float f32x4;
typedef __attribute__((ext_vector_type(8))) short s16x8;
typedef __attribute__((ext_vector_type(8))) unsigned short u16x8;
typedef __attribute__((ext_vector_type(2))) unsigned int u32x2;

#define DEVFN static __device__ __forceinline__

DEVFN unsigned short f2bf(float f) {
  union { float f; unsigned int u; } v; v.f = f;
  unsigned int u = v.u;
  u += 0x7fffu + ((u >> 16) & 1u);   // RNE
  return (unsigned short)(u >> 16);
}

DEVFN unsigned int cvt_pk(float a, float b) {
  __hip_bfloat162 h = __float22bfloat162_rn(make_float2(a, b));
  union { __hip_bfloat162 h; unsigned int u; } v; v.h = h; return v.u;
}

DEVFN void gl_lds16(const void* g, void* l) {
  __builtin_amdgcn_global_load_lds((__attribute__((address_space(1))) void*)g,
                                   (__attribute__((address_space(3))) void*)l, 16, 0, 0);
}

// ws layout (bytes)
#define DG_OFF 0
#define DB_OFF 2048
#define UG_OFF 4096
#define UB_OFF 12288
#define W1_BYTE   81920      // [2 ntile][16 kc][128 n][64 k] bf16 swizzled  (512 KB)
#define W2_BYTE   606208     // [8 ntile][4 kc][128 n][64 k] bf16 swizzled   (512 KB)
#define ASUM_BYTE 1130496    // float asum_part[2][32768]                    (256 KB)
#define ACT_BYTE  1392640    // [256 mtile][4 kc][128 r][64 k] bf16 swizzled (16 MB)

// ---------- coefficient GEMMs: conditions[8,512] @ {gamma,beta} ----------
__global__ void coef_kernel(const float* __restrict__ cond,
                            const float* __restrict__ dgm, const float* __restrict__ dbt,
                            const float* __restrict__ ugm, const float* __restrict__ ubt,
                            float* __restrict__ coef) {
  __shared__ float lc[4096];
  __shared__ float red[2048];
  const int t = threadIdx.x;
#pragma unroll
  for (int i = 0; i < 16; ++i) lc[t + i * 256] = cond[t + i * 256];
  __syncthreads();
  const int col = blockIdx.x * 16 + (t & 15);
  const int ks = t >> 4;
  const float* src; int ncol, cl;
  if (col < 256)       { src = dgm; ncol = 256;  cl = col; }
  else if (col < 512)  { src = dbt; ncol = 256;  cl = col - 256; }
  else if (col < 1536) { src = ugm; ncol = 1024; cl = col - 512; }
  else                 { src = ubt; ncol = 1024; cl = col - 1536; }
  float acc[8] = {};
  for (int k = ks * 32; k < ks * 32 + 32; ++k) {
    float g = src[(size_t)k * ncol + cl];
#pragma unroll
    for (int b = 0; b < 8; ++b) acc[b] = fmaf(lc[b * 512 + k], g, acc[b]);
  }
#pragma unroll
  for (int b = 0; b < 8; ++b) red[(ks * 16 + (t & 15)) * 8 + b] = acc[b];
  __syncthreads();
  if (t < 128) {
    int c = t >> 3, b = t & 7;
    float s = 0.f;
#pragma unroll
    for (int k2 = 0; k2 < 16; ++k2) s += red[(k2 * 16 + c) * 8 + b];
    int colg = blockIdx.x * 16 + c;
    float* dst; int ncol2, cl2;
    if (colg < 256)       { dst = coef + DG_OFF; ncol2 = 256;  cl2 = colg; }
    else if (colg < 512)  { dst = coef + DB_OFF; ncol2 = 256;  cl2 = colg - 256; }
    else if (colg < 1536) { dst = coef + UG_OFF; ncol2 = 1024; cl2 = colg - 512; }
    else                  { dst = coef + UB_OFF; ncol2 = 1024; cl2 = colg - 1536; }
    dst[b * ncol2 + cl2] = s;
  }
}

// ---------- build pre-swizzled bf16 weight images ----------
// image chunk = [128 n][64 k] bf16, 16B granule g at byte n*128 + ((g^(n&7))<<4)
__global__ void wimg_kernel(const float* __restrict__ Wd, const float* __restrict__ Wu,
                            char* __restrict__ ws) {
  const int bid = blockIdx.x;
  const float* src; char* dst; int C, ntile, kc;
  if (bid < 32) { src = Wd; C = 256;  ntile = bid >> 4; kc = bid & 15;
                  dst = ws + W1_BYTE + (size_t)(ntile * 16 + kc) * 16384; }
  else { int b2 = bid - 32; src = Wu; C = 1024; ntile = b2 >> 2; kc = b2 & 3;
         dst = ws + W2_BYTE + (size_t)(ntile * 4 + kc) * 16384; }
  const int t = threadIdx.x;
  const int n = t >> 1, kh = t & 1;
  const float* sp = src + (size_t)(kc * 64 + kh * 32) * C + ntile * 128 + n;
  unsigned short tmp[32];
#pragma unroll
  for (int kk = 0; kk < 32; ++kk) tmp[kk] = f2bf(sp[(size_t)kk * C]);
  char* drow = dst + n * 128;
#pragma unroll
  for (int gi = 0; gi < 4; ++gi) {
    u16x8 v;
#pragma unroll
    for (int e = 0; e < 8; ++e) v[e] = tmp[gi * 8 + e];
    int g = kh * 4 + gi;
    *(u16x8*)(drow + ((g ^ (n & 7)) << 4)) = v;
  }
}

// ---------- GEMM1: act_img = relu(dg ∘ (X @ Wd) + db ∘ rowsum(X)) ----------
// BM=128, BN=128 (ntile of H=256), BK=64, 4 waves (2m x 2n), wave tile 64x64
__global__ __launch_bounds__(256, 2)
void gemm1_kernel(const float* __restrict__ X, char* __restrict__ ws) {
  __shared__ char lds[65536];   // Xs0/Xs1 @0/16K, Ws0/Ws1 @32K/48K
  const int tid = threadIdx.x;
  const int lane = tid & 63, wave = tid >> 6;
  const int lr = lane & 15, lq = lane >> 4;
  const int wm = wave >> 1, wn = wave & 1;

  const int raw = blockIdx.x;
  const int swz = (raw & 7) * 64 + (raw >> 3);      // XCD-chunked, 512 % 8 == 0
  const int m = swz >> 1, ntile = swz & 1;
  const int row0 = m << 7;
  const int b = m >> 5;

  const float* coef = (const float*)ws;
  const char* w1img = ws + W1_BYTE + (size_t)(ntile * 16) * 16384;
  float* asump = (float*)(ws + ASUM_BYTE);

  // staging: thread covers rows srow+16j, cols scol*4..+3 of the [128][64] chunk
  const int srow = tid >> 4, scol = tid & 15;
  const float* xptr = X + (size_t)(row0 + srow) * 1024 + scol * 4;
  int xw[8];
#pragma unroll
  for (int j = 0; j < 8; ++j) {
    int r = srow + 16 * j;
    xw[j] = r * 128 + (((scol >> 1) ^ (r & 7)) << 4) + ((scol & 1) ? 8 : 0);
  }
  int aoff[4][2], boff[4][2];
#pragma unroll
  for (int mf = 0; mf < 4; ++mf)
#pragma unroll
    for (int kf = 0; kf < 2; ++kf) {
      int r = wm * 64 + mf * 16 + lr;
      aoff[mf][kf] = r * 128 + (((kf * 4 + lq) ^ (r & 7)) << 4);
    }
#pragma unroll
  for (int nf = 0; nf < 4; ++nf)
#pragma unroll
    for (int kf = 0; kf < 2; ++kf) {
      int n = wn * 64 + nf * 16 + lr;
      boff[nf][kf] = n * 128 + (((kf * 4 + lq) ^ (n & 7)) << 4);
    }

  f32x4 acc[4][4] = {};
  float hacc[8] = {};
  f32x4 xv[8];

  // prologue: stage kc=0 into buf0
#pragma unroll
  for (int i = 0; i < 4; ++i)
    gl_lds16(w1img + (wave * 4 + i) * 1024 + lane * 16, lds + 32768 + (wave * 4 + i) * 1024);
#pragma unroll
  for (int j = 0; j < 8; ++j) xv[j] = *(const f32x4*)(xptr + (size_t)(16 * j) * 1024);
#pragma unroll
  for (int j = 0; j < 8; ++j) {
    hacc[j] += xv[j][0] + xv[j][1] + xv[j][2] + xv[j][3];
    u32x2 p; p[0] = cvt_pk(xv[j][0], xv[j][1]); p[1] = cvt_pk(xv[j][2], xv[j][3]);
    *(u32x2*)(lds + xw[j]) = p;
  }
  __syncthreads();

  for (int t = 0; t < 16; ++t) {
    const int cur = t & 1, nxt = cur ^ 1;
    if (t < 15) {
      const char* wsrc = w1img + (size_t)(t + 1) * 16384;
#pragma unroll
      for (int i = 0; i < 4; ++i)
        gl_lds16(wsrc + (wave * 4 + i) * 1024 + lane * 16,
                 lds + 32768 + nxt * 16384 + (wave * 4 + i) * 1024);
      const float* xs = xptr + (t + 1) * 64;
#pragma unroll
      for (int j = 0; j < 8; ++j) xv[j] = *(const f32x4*)(xs + (size_t)(16 * j) * 1024);
    }
    const char* Xc = lds + cur * 16384;
    const char* Wc = lds + 32768 + cur * 16384;
#pragma unroll
    for (int kf = 0; kf < 2; ++kf) {
      s16x8 a[4], bb[4];
#pragma unroll
      for (int mf = 0; mf < 4; ++mf) a[mf] = *(const s16x8*)(Xc + aoff[mf][kf]);
#pragma unroll
      for (int nf = 0; nf < 4; ++nf) bb[nf] = *(const s16x8*)(Wc + boff[nf][kf]);
#pragma unroll
      for (int mf = 0; mf < 4; ++mf)
#pragma unroll
        for (int nf = 0; nf < 4; ++nf)
          acc[mf][nf] = __builtin_amdgcn_mfma_f32_16x16x32_bf16(a[mf], bb[nf], acc[mf][nf], 0, 0, 0);
    }
    if (t < 15) {
      char* Xn = lds + nxt * 16384;
#pragma unroll
      for (int j = 0; j < 8; ++j) {
        hacc[j] += xv[j][0] + xv[j][1] + xv[j][2] + xv[j][3];
        u32x2 p; p[0] = cvt_pk(xv[j][0], xv[j][1]); p[1] = cvt_pk(xv[j][2], xv[j][3]);
        *(u32x2*)(Xn + xw[j]) = p;
      }
    }
    __syncthreads();
  }

  // ---- epilogue ----
  // LDS reuse: hsumb @0 (512B), asumb @512 (1KB), repack @2048 (32KB)
  float* hsumb = (float*)lds;
  float* asumb = (float*)(lds + 512);
  char* rep = lds + 2048;
#pragma unroll
  for (int j = 0; j < 8; ++j) {
    float s = hacc[j];
    s += __shfl_xor(s, 1); s += __shfl_xor(s, 2); s += __shfl_xor(s, 4); s += __shfl_xor(s, 8);
    if (lr == 0) hsumb[wave * 4 + lq + 16 * j] = s;
  }
  __syncthreads();

  float dgv[4], dbv[4];
#pragma unroll
  for (int nf = 0; nf < 4; ++nf) {
    int h = ntile * 128 + wn * 64 + nf * 16 + lr;
    dgv[nf] = coef[DG_OFF + b * 256 + h];
    dbv[nf] = coef[DB_OFF + b * 256 + h];
  }

  // modulate + relu -> repack into LDS replica of the act-image region.
  // local h = wn*64 + nf*16 + lr, so chunk c == wn, kl = nf*16+lr.
  float asacc[4][4] = {};
#pragma unroll
  for (int nf = 0; nf < 4; ++nf) {
    int g = nf * 2 + (lr >> 3);
    char* nbase = rep + wn * 16384 + (lr & 7) * 2;
    float dg_ = dgv[nf], db_ = dbv[nf];
#pragma unroll
    for (int mf = 0; mf < 4; ++mf) {
      int rb = wm * 64 + mf * 16 + lq * 4;
#pragma unroll
      for (int j = 0; j < 4; ++j) {
        int r = rb + j;
        float v = acc[mf][nf][j] * dg_ + db_ * hsumb[r];
        v = fmaxf(v, 0.f);
        asacc[mf][j] += v;
        *(unsigned short*)(nbase + r * 128 + ((g ^ (r & 7)) << 4)) = f2bf(v);
      }
    }
  }
#pragma unroll
  for (int mf = 0; mf < 4; ++mf)
#pragma unroll
    for (int j = 0; j < 4; ++j) {
      float s = asacc[mf][j];
      s += __shfl_xor(s, 1); s += __shfl_xor(s, 2); s += __shfl_xor(s, 4); s += __shfl_xor(s, 8);
      if (lr == 0) asumb[wn * 128 + wm * 64 + mf * 16 + lq * 4 + j] = s;
    }
  __syncthreads();

  // coalesced copy-out: 32KB linear -> act image (chunks ntile*2, ntile*2+1)
  char* actb = ws + ACT_BYTE + (size_t)m * 65536 + (size_t)ntile * 32768;
#pragma unroll
  for (int i = 0; i < 8; ++i) {
    int o = i * 4096 + tid * 16;
    u16x8 v = *(const u16x8*)(rep + o);
    *(u16x8*)(actb + o) = v;
  }
  if (tid < 128) asump[ntile * 32768 + row0 + tid] = asumb[tid] + asumb[128 + tid];
}

// ---------- GEMM2: out = ug ∘ (act @ Wu) + ub ∘ rowsum(act) + X ----------
// BM=128, BN=128 (8 ntiles of D=1024), BK=64, K=256, both operands via global_load_lds
__global__ __launch_bounds__(256, 2)
void gemm2_kernel(const float* __restrict__ X, const char* __restrict__ ws,
                  float* __restrict__ out) {
  __shared__ char lds[65536];
  const int tid = threadIdx.x;
  const int lane = tid & 63, wave = tid >> 6;
  const int lr = lane & 15, lq = lane >> 4;
  const int wm = wave >> 1, wn = wave & 1;

  const int raw = blockIdx.x;
  const int swz = (raw & 7) * 256 + (raw >> 3);     // 2048 % 8 == 0
  const int m = swz >> 3, nt = swz & 7;
  const int row0 = m << 7, n0 = nt << 7;
  const int b = m >> 5;

  const float* coef = (const float*)ws;
  const char* aimg = ws + ACT_BYTE + (size_t)m * 65536;
  const char* wimg = ws + W2_BYTE + (size_t)(nt * 4) * 16384;
  const float* asump = (const float*)(ws + ASUM_BYTE);

  int aoff[4][2], boff[4][2];
#pragma unroll
  for (int mf = 0; mf < 4; ++mf)
#pragma unroll
    for (int kf = 0; kf < 2; ++kf) {
      int r = wm * 64 + mf * 16 + lr;
      aoff[mf][kf] = r * 128 + (((kf * 4 + lq) ^ (r & 7)) << 4);
    }
#pragma unroll
  for (int nf = 0; nf < 4; ++nf)
#pragma unroll
    for (int kf = 0; kf < 2; ++kf) {
      int n = wn * 64 + nf * 16 + lr;
      boff[nf][kf] = n * 128 + (((kf * 4 + lq) ^ (n & 7)) << 4);
    }

  f32x4 acc[4][4] = {};

#pragma unroll
  for (int i = 0; i < 4; ++i) {
    gl_lds16(aimg + (wave * 4 + i) * 1024 + lane * 16, lds + (wave * 4 + i) * 1024);
    gl_lds16(wimg + (wave * 4 + i) * 1024 + lane * 16, lds + 32768 + (wave * 4 + i) * 1024);
  }
  __syncthreads();

  for (int t = 0; t < 4; ++t) {
    const int cur = t & 1, nxt = cur ^ 1;
    if (t < 3) {
#pragma unroll
      for (int i = 0; i < 4; ++i) {
        gl_lds16(aimg + (size_t)(t + 1) * 16384 + (wave * 4 + i) * 1024 + lane * 16,
                 lds + nxt * 16384 + (wave * 4 + i) * 1024);
        gl_lds16(wimg + (size_t)(t + 1) * 16384 + (wave * 4 + i) * 1024 + lane * 16,
                 lds + 32768 + nxt * 16384 + (wave * 4 + i) * 1024);
      }
    }
    const char* Ac = lds + cur * 16384;
    const char* Wc = lds + 32768 + cur * 16384;
#pragma unroll
    for (int kf = 0; kf < 2; ++kf) {
      s16x8 a[4], bb[4];
#pragma unroll
      for (int mf = 0; mf < 4; ++mf) a[mf] = *(const s16x8*)(Ac + aoff[mf][kf]);
#pragma unroll
      for (int nf = 0; nf < 4; ++nf) bb[nf] = *(const s16x8*)(Wc + boff[nf][kf]);
#pragma unroll
      for (int mf = 0; mf < 4; ++mf)
#pragma unroll
        for (int nf = 0; nf < 4; ++nf)
          acc[mf][nf] = __builtin_amdgcn_mfma_f32_16x16x32_bf16(a[mf], bb[nf], acc[mf][nf], 0, 0, 0);
    }
    __syncthreads();
  }

  // ---- epilogue: modulate into LDS f32 tile [128r][128n] (row 512B, XOR-swizzled
  // 16B granules), then coalesced copy-out fused with residual add ----
  float ugv[4], ubv[4];
#pragma unroll
  for (int nf = 0; nf < 4; ++nf) {
    int d = n0 + wn * 64 + nf * 16 + lr;
    ugv[nf] = coef[UG_OFF + b * 1024 + d];
    ubv[nf] = coef[UB_OFF + b * 1024 + d];
  }
#pragma unroll
  for (int mf = 0; mf < 4; ++mf) {
#pragma unroll
    for (int j = 0; j < 4; ++j) {
      int rl = wm * 64 + mf * 16 + lq * 4 + j;
      int rg = row0 + rl;
      float as = asump[rg] + asump[32768 + rg];
#pragma unroll
      for (int nf = 0; nf < 4; ++nf) {
        int nl = wn * 64 + nf * 16 + lr;
        float v = acc[mf][nf][j] * ugv[nf] + ubv[nf] * as;
        *(float*)(lds + rl * 512 + ((((nl >> 2) ^ (rl & 7)) << 4) + (nl & 3) * 4)) = v;
      }
    }
  }
  __syncthreads();
#pragma unroll
  for (int i = 0; i < 16; ++i) {
    int o = i * 4096 + tid * 16;
    int rl = o >> 9, part = o & 511;
    int gg = ((part >> 4) ^ (rl & 7));
    f32x4 v = *(const f32x4*)(lds + rl * 512 + (gg << 4));
    size_t gfo = (size_t)(row0 + rl) * 1024 + n0 + (part >> 2);
    f32x4 x = *(const f32x4*)(X + gfo);
    *(f32x4*)(out + gfo) = v + x;
  }
}

extern "C" void kernel_launch(void* const* d_in, const int* in_sizes, int n_in,
                              void* d_out, int out_size, void* d_ws, size_t ws_size,
                              hipStream_t stream) {
  const float* hidden       = (const float*)d_in[0];
  const float* conditions   = (const float*)d_in[1];
  const float* down_project = (const float*)d_in[2];
  const float* down_gamma   = (const float*)d_in[3];
  const float* down_beta    = (const float*)d_in[4];
  const float* up_project   = (const float*)d_in[5];
  const float* up_gamma     = (const float*)d_in[6];
  const float* up_beta      = (const float*)d_in[7];
  float* out = (float*)d_out;
  char* ws = (char*)d_ws;

  coef_kernel<<<160, 256, 0, stream>>>(conditions, down_gamma, down_beta, up_gamma, up_beta,
                                       (float*)ws);
  wimg_kernel<<<64, 256, 0, stream>>>(down_project, up_project, ws);
  gemm1_kernel<<<512, 256, 0, stream>>>(hidden, ws);
  gemm2_kernel<<<2048, 256, 0, stream>>>(hidden, ws, out);
}

// Round 4
// 105.066 us; speedup vs baseline: 1.1105x; 1.1105x over previous
//
#include <hip/hip_runtime.h>
#include <hip/hip_bf16.h>

typedef __attribute__((ext_vector_type(4))) float f32x4;
typedef __attribute__((ext_vector_type(8))) short s16x8;
typedef __attribute__((ext_vector_type(8))) unsigned short u16x8;
typedef __attribute__((ext_vector_type(2))) unsigned int u32x2;

#define DEVFN static __device__ __forceinline__

DEVFN unsigned short f2bf(float f) {
  union { float f; unsigned int u; } v; v.f = f;
  unsigned int u = v.u;
  u += 0x7fffu + ((u >> 16) & 1u);   // RNE
  return (unsigned short)(u >> 16);
}

DEVFN unsigned int cvt_pk(float a, float b) {
  __hip_bfloat162 h = __float22bfloat162_rn(make_float2(a, b));
  union { __hip_bfloat162 h; unsigned int u; } v; v.h = h; return v.u;
}

DEVFN void gl_lds16(const void* g, void* l) {
  __builtin_amdgcn_global_load_lds((__attribute__((address_space(1))) void*)g,
                                   (__attribute__((address_space(3))) void*)l, 16, 0, 0);
}

// pinned async register load: cannot be sunk into its use site by the scheduler
DEVFN f32x4 async_ld(const float* p) {
  f32x4 v;
  asm volatile("global_load_dwordx4 %0, %1, off"
               : "=v"(v)
               : "v"((unsigned long long)(uintptr_t)p)
               : "memory");
  return v;
}

// ws layout (bytes)
#define DG_OFF 0
#define DB_OFF 2048
#define UG_OFF 4096
#define UB_OFF 12288
#define W1_BYTE   81920      // [2 ntile][16 kc][128 n][64 k] bf16 swizzled  (512 KB)
#define W2_BYTE   606208     // [8 ntile][4 kc][128 n][64 k] bf16 swizzled   (512 KB)
#define ASUM_BYTE 1130496    // float asum_part[2][32768]                    (256 KB)
#define ACT_BYTE  1392640    // [256 mtile][4 kc][128 r][64 k] bf16 swizzled (16 MB)

// ---------- coefficient GEMMs: conditions[8,512] @ {gamma,beta} ----------
__global__ void coef_kernel(const float* __restrict__ cond,
                            const float* __restrict__ dgm, const float* __restrict__ dbt,
                            const float* __restrict__ ugm, const float* __restrict__ ubt,
                            float* __restrict__ coef) {
  __shared__ float lc[4096];
  __shared__ float red[2048];
  const int t = threadIdx.x;
#pragma unroll
  for (int i = 0; i < 16; ++i) lc[t + i * 256] = cond[t + i * 256];
  __syncthreads();
  const int col = blockIdx.x * 16 + (t & 15);
  const int ks = t >> 4;
  const float* src; int ncol, cl;
  if (col < 256)       { src = dgm; ncol = 256;  cl = col; }
  else if (col < 512)  { src = dbt; ncol = 256;  cl = col - 256; }
  else if (col < 1536) { src = ugm; ncol = 1024; cl = col - 512; }
  else                 { src = ubt; ncol = 1024; cl = col - 1536; }
  float acc[8] = {};
  for (int k = ks * 32; k < ks * 32 + 32; ++k) {
    float g = src[(size_t)k * ncol + cl];
#pragma unroll
    for (int b = 0; b < 8; ++b) acc[b] = fmaf(lc[b * 512 + k], g, acc[b]);
  }
#pragma unroll
  for (int b = 0; b < 8; ++b) red[(ks * 16 + (t & 15)) * 8 + b] = acc[b];
  __syncthreads();
  if (t < 128) {
    int c = t >> 3, b = t & 7;
    float s = 0.f;
#pragma unroll
    for (int k2 = 0; k2 < 16; ++k2) s += red[(k2 * 16 + c) * 8 + b];
    int colg = blockIdx.x * 16 + c;
    float* dst; int ncol2, cl2;
    if (colg < 256)       { dst = coef + DG_OFF; ncol2 = 256;  cl2 = colg; }
    else if (colg < 512)  { dst = coef + DB_OFF; ncol2 = 256;  cl2 = colg - 256; }
    else if (colg < 1536) { dst = coef + UG_OFF; ncol2 = 1024; cl2 = colg - 512; }
    else                  { dst = coef + UB_OFF; ncol2 = 1024; cl2 = colg - 1536; }
    dst[b * ncol2 + cl2] = s;
  }
}

// ---------- build pre-swizzled bf16 weight images ----------
// image chunk = [128 n][64 k] bf16, 16B granule g at byte n*128 + ((g^(n&7))<<4)
__global__ void wimg_kernel(const float* __restrict__ Wd, const float* __restrict__ Wu,
                            char* __restrict__ ws) {
  const int bid = blockIdx.x;
  const float* src; char* dst; int C, ntile, kc;
  if (bid < 32) { src = Wd; C = 256;  ntile = bid >> 4; kc = bid & 15;
                  dst = ws + W1_BYTE + (size_t)(ntile * 16 + kc) * 16384; }
  else { int b2 = bid - 32; src = Wu; C = 1024; ntile = b2 >> 2; kc = b2 & 3;
         dst = ws + W2_BYTE + (size_t)(ntile * 4 + kc) * 16384; }
  const int t = threadIdx.x;
  const int n = t >> 1, kh = t & 1;
  const float* sp = src + (size_t)(kc * 64 + kh * 32) * C + ntile * 128 + n;
  unsigned short tmp[32];
#pragma unroll
  for (int kk = 0; kk < 32; ++kk) tmp[kk] = f2bf(sp[(size_t)kk * C]);
  char* drow = dst + n * 128;
#pragma unroll
  for (int gi = 0; gi < 4; ++gi) {
    u16x8 v;
#pragma unroll
    for (int e = 0; e < 8; ++e) v[e] = tmp[gi * 8 + e];
    int g = kh * 4 + gi;
    *(u16x8*)(drow + ((g ^ (n & 7)) << 4)) = v;
  }
}

// ---------- GEMM1: act_img = relu(dg ∘ (X @ Wd) + db ∘ rowsum(X)) ----------
// BM=128, BN=128 (ntile of H=256), BK=64, 4 waves (2m x 2n), wave tile 64x64
// X staging: T14 async split — asm-pinned loads early, counted vmcnt + cvt late.
__global__ __launch_bounds__(256, 2)
void gemm1_kernel(const float* __restrict__ X, char* __restrict__ ws) {
  __shared__ char lds[65536];   // Xs0/Xs1 @0/16K, Ws0/Ws1 @32K/48K
  const int tid = threadIdx.x;
  const int lane = tid & 63, wave = tid >> 6;
  const int lr = lane & 15, lq = lane >> 4;
  const int wm = wave >> 1, wn = wave & 1;

  const int raw = blockIdx.x;
  const int swz = (raw & 7) * 64 + (raw >> 3);      // XCD-chunked, 512 % 8 == 0
  const int m = swz >> 1, ntile = swz & 1;
  const int row0 = m << 7;
  const int b = m >> 5;

  const float* coef = (const float*)ws;
  const char* w1img = ws + W1_BYTE + (size_t)(ntile * 16) * 16384;
  float* asump = (float*)(ws + ASUM_BYTE);

  // staging: thread covers rows srow+16j, cols scol*4..+3 of the [128][64] chunk
  const int srow = tid >> 4, scol = tid & 15;
  const float* xptr = X + (size_t)(row0 + srow) * 1024 + scol * 4;
  int xw[8];
#pragma unroll
  for (int j = 0; j < 8; ++j) {
    int r = srow + 16 * j;
    xw[j] = r * 128 + (((scol >> 1) ^ (r & 7)) << 4) + ((scol & 1) ? 8 : 0);
  }
  int aoff[4][2], boff[4][2];
#pragma unroll
  for (int mf = 0; mf < 4; ++mf)
#pragma unroll
    for (int kf = 0; kf < 2; ++kf) {
      int r = wm * 64 + mf * 16 + lr;
      aoff[mf][kf] = r * 128 + (((kf * 4 + lq) ^ (r & 7)) << 4);
    }
#pragma unroll
  for (int nf = 0; nf < 4; ++nf)
#pragma unroll
    for (int kf = 0; kf < 2; ++kf) {
      int n = wn * 64 + nf * 16 + lr;
      boff[nf][kf] = n * 128 + (((kf * 4 + lq) ^ (n & 7)) << 4);
    }

  f32x4 acc[4][4] = {};
  float hacc[8] = {};
  f32x4 xv[8];

  // ---- prologue: stage kc=0 into buf0 ----
#pragma unroll
  for (int j = 0; j < 8; ++j) xv[j] = async_ld(xptr + (size_t)(16 * j) * 1024);
#pragma unroll
  for (int i = 0; i < 4; ++i)
    gl_lds16(w1img + (wave * 4 + i) * 1024 + lane * 16, lds + 32768 + (wave * 4 + i) * 1024);
  asm volatile("s_waitcnt vmcnt(4)" ::: "memory");
  __builtin_amdgcn_sched_barrier(0);
#pragma unroll
  for (int j = 0; j < 8; ++j) {
    hacc[j] += xv[j][0] + xv[j][1] + xv[j][2] + xv[j][3];
    u32x2 p; p[0] = cvt_pk(xv[j][0], xv[j][1]); p[1] = cvt_pk(xv[j][2], xv[j][3]);
    *(u32x2*)(lds + xw[j]) = p;
  }
  __syncthreads();

  for (int t = 0; t < 16; ++t) {
    const int cur = t & 1, nxt = cur ^ 1;
    if (t < 15) {
      // step 1: pinned async X loads for tile t+1 (8 oldest vmem ops)
      const float* xs = xptr + (t + 1) * 64;
#pragma unroll
      for (int j = 0; j < 8; ++j) xv[j] = async_ld(xs + (size_t)(16 * j) * 1024);
      // step 2: W prefetch for tile t+1 (4 newest vmem ops)
      const char* wsrc = w1img + (size_t)(t + 1) * 16384;
#pragma unroll
      for (int i = 0; i < 4; ++i)
        gl_lds16(wsrc + (wave * 4 + i) * 1024 + lane * 16,
                 lds + 32768 + nxt * 16384 + (wave * 4 + i) * 1024);
    }
    // step 3: MFMA on current buffers (covers the X-load latency)
    const char* Xc = lds + cur * 16384;
    const char* Wc = lds + 32768 + cur * 16384;
#pragma unroll
    for (int kf = 0; kf < 2; ++kf) {
      s16x8 a[4], bb[4];
#pragma unroll
      for (int mf = 0; mf < 4; ++mf) a[mf] = *(const s16x8*)(Xc + aoff[mf][kf]);
#pragma unroll
      for (int nf = 0; nf < 4; ++nf) bb[nf] = *(const s16x8*)(Wc + boff[nf][kf]);
#pragma unroll
      for (int mf = 0; mf < 4; ++mf)
#pragma unroll
        for (int nf = 0; nf < 4; ++nf)
          acc[mf][nf] = __builtin_amdgcn_mfma_f32_16x16x32_bf16(a[mf], bb[nf], acc[mf][nf], 0, 0, 0);
    }
    if (t < 15) {
      // step 4: wait only the 8 X loads (leave the 4 gl_lds in flight)
      asm volatile("s_waitcnt vmcnt(4)" ::: "memory");
      __builtin_amdgcn_sched_barrier(0);
      // step 5: convert + rowsum + LDS write into next buffer
      char* Xn = lds + nxt * 16384;
#pragma unroll
      for (int j = 0; j < 8; ++j) {
        hacc[j] += xv[j][0] + xv[j][1] + xv[j][2] + xv[j][3];
        u32x2 p; p[0] = cvt_pk(xv[j][0], xv[j][1]); p[1] = cvt_pk(xv[j][2], xv[j][3]);
        *(u32x2*)(Xn + xw[j]) = p;
      }
    }
    __syncthreads();
  }

  // ---- epilogue ----
  // LDS reuse: hsumb @0 (512B), asumb @512 (1KB), repack @2048 (32KB)
  float* hsumb = (float*)lds;
  float* asumb = (float*)(lds + 512);
  char* rep = lds + 2048;
#pragma unroll
  for (int j = 0; j < 8; ++j) {
    float s = hacc[j];
    s += __shfl_xor(s, 1); s += __shfl_xor(s, 2); s += __shfl_xor(s, 4); s += __shfl_xor(s, 8);
    if (lr == 0) hsumb[wave * 4 + lq + 16 * j] = s;
  }
  __syncthreads();

  float dgv[4], dbv[4];
#pragma unroll
  for (int nf = 0; nf < 4; ++nf) {
    int h = ntile * 128 + wn * 64 + nf * 16 + lr;
    dgv[nf] = coef[DG_OFF + b * 256 + h];
    dbv[nf] = coef[DB_OFF + b * 256 + h];
  }

  // modulate + relu -> repack into LDS replica of the act-image region.
  float asacc[4][4] = {};
#pragma unroll
  for (int nf = 0; nf < 4; ++nf) {
    int g = nf * 2 + (lr >> 3);
    char* nbase = rep + wn * 16384 + (lr & 7) * 2;
    float dg_ = dgv[nf], db_ = dbv[nf];
#pragma unroll
    for (int mf = 0; mf < 4; ++mf) {
      int rb = wm * 64 + mf * 16 + lq * 4;
#pragma unroll
      for (int j = 0; j < 4; ++j) {
        int r = rb + j;
        float v = acc[mf][nf][j] * dg_ + db_ * hsumb[r];
        v = fmaxf(v, 0.f);
        asacc[mf][j] += v;
        *(unsigned short*)(nbase + r * 128 + ((g ^ (r & 7)) << 4)) = f2bf(v);
      }
    }
  }
#pragma unroll
  for (int mf = 0; mf < 4; ++mf)
#pragma unroll
    for (int j = 0; j < 4; ++j) {
      float s = asacc[mf][j];
      s += __shfl_xor(s, 1); s += __shfl_xor(s, 2); s += __shfl_xor(s, 4); s += __shfl_xor(s, 8);
      if (lr == 0) asumb[wn * 128 + wm * 64 + mf * 16 + lq * 4 + j] = s;
    }
  __syncthreads();

  // coalesced copy-out: 32KB linear -> act image (chunks ntile*2, ntile*2+1)
  char* actb = ws + ACT_BYTE + (size_t)m * 65536 + (size_t)ntile * 32768;
#pragma unroll
  for (int i = 0; i < 8; ++i) {
    int o = i * 4096 + tid * 16;
    u16x8 v = *(const u16x8*)(rep + o);
    *(u16x8*)(actb + o) = v;
  }
  if (tid < 128) asump[ntile * 32768 + row0 + tid] = asumb[tid] + asumb[128 + tid];
}

// ---------- GEMM2: out = ug ∘ (act @ Wu) + ub ∘ rowsum(act) + X ----------
// BM=128, BN=128 (8 ntiles of D=1024), BK=64, K=256, both operands via global_load_lds
__global__ __launch_bounds__(256, 2)
void gemm2_kernel(const float* __restrict__ X, const char* __restrict__ ws,
                  float* __restrict__ out) {
  __shared__ char lds[65536];
  const int tid = threadIdx.x;
  const int lane = tid & 63, wave = tid >> 6;
  const int lr = lane & 15, lq = lane >> 4;
  const int wm = wave >> 1, wn = wave & 1;

  const int raw = blockIdx.x;
  const int swz = (raw & 7) * 256 + (raw >> 3);     // 2048 % 8 == 0
  const int m = swz >> 3, nt = swz & 7;
  const int row0 = m << 7, n0 = nt << 7;
  const int b = m >> 5;

  const float* coef = (const float*)ws;
  const char* aimg = ws + ACT_BYTE + (size_t)m * 65536;
  const char* wimg = ws + W2_BYTE + (size_t)(nt * 4) * 16384;
  const float* asump = (const float*)(ws + ASUM_BYTE);

  int aoff[4][2], boff[4][2];
#pragma unroll
  for (int mf = 0; mf < 4; ++mf)
#pragma unroll
    for (int kf = 0; kf < 2; ++kf) {
      int r = wm * 64 + mf * 16 + lr;
      aoff[mf][kf] = r * 128 + (((kf * 4 + lq) ^ (r & 7)) << 4);
    }
#pragma unroll
  for (int nf = 0; nf < 4; ++nf)
#pragma unroll
    for (int kf = 0; kf < 2; ++kf) {
      int n = wn * 64 + nf * 16 + lr;
      boff[nf][kf] = n * 128 + (((kf * 4 + lq) ^ (n & 7)) << 4);
    }

  f32x4 acc[4][4] = {};

#pragma unroll
  for (int i = 0; i < 4; ++i) {
    gl_lds16(aimg + (wave * 4 + i) * 1024 + lane * 16, lds + (wave * 4 + i) * 1024);
    gl_lds16(wimg + (wave * 4 + i) * 1024 + lane * 16, lds + 32768 + (wave * 4 + i) * 1024);
  }
  __syncthreads();

  for (int t = 0; t < 4; ++t) {
    const int cur = t & 1, nxt = cur ^ 1;
    if (t < 3) {
#pragma unroll
      for (int i = 0; i < 4; ++i) {
        gl_lds16(aimg + (size_t)(t + 1) * 16384 + (wave * 4 + i) * 1024 + lane * 16,
                 lds + nxt * 16384 + (wave * 4 + i) * 1024);
        gl_lds16(wimg + (size_t)(t + 1) * 16384 + (wave * 4 + i) * 1024 + lane * 16,
                 lds + 32768 + nxt * 16384 + (wave * 4 + i) * 1024);
      }
    }
    const char* Ac = lds + cur * 16384;
    const char* Wc = lds + 32768 + cur * 16384;
#pragma unroll
    for (int kf = 0; kf < 2; ++kf) {
      s16x8 a[4], bb[4];
#pragma unroll
      for (int mf = 0; mf < 4; ++mf) a[mf] = *(const s16x8*)(Ac + aoff[mf][kf]);
#pragma unroll
      for (int nf = 0; nf < 4; ++nf) bb[nf] = *(const s16x8*)(Wc + boff[nf][kf]);
#pragma unroll
      for (int mf = 0; mf < 4; ++mf)
#pragma unroll
        for (int nf = 0; nf < 4; ++nf)
          acc[mf][nf] = __builtin_amdgcn_mfma_f32_16x16x32_bf16(a[mf], bb[nf], acc[mf][nf], 0, 0, 0);
    }
    __syncthreads();
  }

  // ---- epilogue: modulate into LDS f32 tile [128r][128n] (row 512B, XOR-swizzled
  // 16B granules), then coalesced copy-out fused with residual add ----
  float ugv[4], ubv[4];
#pragma unroll
  for (int nf = 0; nf < 4; ++nf) {
    int d = n0 + wn * 64 + nf * 16 + lr;
    ugv[nf] = coef[UG_OFF + b * 1024 + d];
    ubv[nf] = coef[UB_OFF + b * 1024 + d];
  }
#pragma unroll
  for (int mf = 0; mf < 4; ++mf) {
#pragma unroll
    for (int j = 0; j < 4; ++j) {
      int rl = wm * 64 + mf * 16 + lq * 4 + j;
      int rg = row0 + rl;
      float as = asump[rg] + asump[32768 + rg];
#pragma unroll
      for (int nf = 0; nf < 4; ++nf) {
        int nl = wn * 64 + nf * 16 + lr;
        float v = acc[mf][nf][j] * ugv[nf] + ubv[nf] * as;
        *(float*)(lds + rl * 512 + ((((nl >> 2) ^ (rl & 7)) << 4) + (nl & 3) * 4)) = v;
      }
    }
  }
  __syncthreads();
#pragma unroll
  for (int i = 0; i < 16; ++i) {
    int o = i * 4096 + tid * 16;
    int rl = o >> 9, part = o & 511;
    int gg = ((part >> 4) ^ (rl & 7));
    f32x4 v = *(const f32x4*)(lds + rl * 512 + (gg << 4));
    size_t gfo = (size_t)(row0 + rl) * 1024 + n0 + (part >> 2);
    f32x4 x = *(const f32x4*)(X + gfo);
    *(f32x4*)(out + gfo) = v + x;
  }
}

extern "C" void kernel_launch(void* const* d_in, const int* in_sizes, int n_in,
                              void* d_out, int out_size, void* d_ws, size_t ws_size,
                              hipStream_t stream) {
  const float* hidden       = (const float*)d_in[0];
  const float* conditions   = (const float*)d_in[1];
  const float* down_project = (const float*)d_in[2];
  const float* down_gamma   = (const float*)d_in[3];
  const float* down_beta    = (const float*)d_in[4];
  const float* up_project   = (const float*)d_in[5];
  const float* up_gamma     = (const float*)d_in[6];
  const float* up_beta      = (const float*)d_in[7];
  float* out = (float*)d_out;
  char* ws = (char*)d_ws;

  coef_kernel<<<160, 256, 0, stream>>>(conditions, down_gamma, down_beta, up_gamma, up_beta,
                                       (float*)ws);
  wimg_kernel<<<64, 256, 0, stream>>>(down_project, up_project, ws);
  gemm1_kernel<<<512, 256, 0, stream>>>(hidden, ws);
  gemm2_kernel<<<2048, 256, 0, stream>>>(hidden, ws, out);
}

// Round 5
// 101.107 us; speedup vs baseline: 1.1540x; 1.0392x over previous
//
#include <hip/hip_runtime.h>
#include <hip/hip_bf16.h>

typedef __attribute__((ext_vector_type(4))) float f32x4;
typedef __attribute__((ext_vector_type(8))) short s16x8;
typedef __attribute__((ext_vector_type(8))) unsigned short u16x8;
typedef __attribute__((ext_vector_type(4))) unsigned int u32x4;

#define DEVFN static __device__ __forceinline__

DEVFN unsigned short f2bf(float f) {
  union { float f; unsigned int u; } v; v.f = f;
  unsigned int u = v.u;
  u += 0x7fffu + ((u >> 16) & 1u);   // RNE
  return (unsigned short)(u >> 16);
}

DEVFN unsigned int cvt_pk(float a, float b) {
  __hip_bfloat162 h = __float22bfloat162_rn(make_float2(a, b));
  union { __hip_bfloat162 h; unsigned int u; } v; v.h = h; return v.u;
}

DEVFN void gl_lds16(const void* g, void* l) {
  __builtin_amdgcn_global_load_lds((__attribute__((address_space(1))) void*)g,
                                   (__attribute__((address_space(3))) void*)l, 16, 0, 0);
}

// ws layout (bytes)
#define DG_OFF 0
#define DB_OFF 2048
#define UG_OFF 4096
#define UB_OFF 12288
#define W1_BYTE   81920      // [2 ntile][16 kc][128 n][64 k] bf16 swizzled  (512 KB)
#define W2_BYTE   606208     // [8 ntile][4 kc][128 n][64 k] bf16 swizzled   (512 KB)
#define ASUM_BYTE 1130496    // float asum_part[2][32768]                    (256 KB)
#define ACT_BYTE  1392640    // [256 mtile][4 kc][128 r][64 k] bf16 swizzled (16 MB)

// ---------- coefficient GEMMs: conditions[8,512] @ {gamma,beta} ----------
__global__ void coef_kernel(const float* __restrict__ cond,
                            const float* __restrict__ dgm, const float* __restrict__ dbt,
                            const float* __restrict__ ugm, const float* __restrict__ ubt,
                            float* __restrict__ coef) {
  __shared__ float lc[4096];
  __shared__ float red[2048];
  const int t = threadIdx.x;
#pragma unroll
  for (int i = 0; i < 16; ++i) lc[t + i * 256] = cond[t + i * 256];
  __syncthreads();
  const int col = blockIdx.x * 16 + (t & 15);
  const int ks = t >> 4;
  const float* src; int ncol, cl;
  if (col < 256)       { src = dgm; ncol = 256;  cl = col; }
  else if (col < 512)  { src = dbt; ncol = 256;  cl = col - 256; }
  else if (col < 1536) { src = ugm; ncol = 1024; cl = col - 512; }
  else                 { src = ubt; ncol = 1024; cl = col - 1536; }
  float acc[8] = {};
  for (int k = ks * 32; k < ks * 32 + 32; ++k) {
    float g = src[(size_t)k * ncol + cl];
#pragma unroll
    for (int b = 0; b < 8; ++b) acc[b] = fmaf(lc[b * 512 + k], g, acc[b]);
  }
#pragma unroll
  for (int b = 0; b < 8; ++b) red[(ks * 16 + (t & 15)) * 8 + b] = acc[b];
  __syncthreads();
  if (t < 128) {
    int c = t >> 3, b = t & 7;
    float s = 0.f;
#pragma unroll
    for (int k2 = 0; k2 < 16; ++k2) s += red[(k2 * 16 + c) * 8 + b];
    int colg = blockIdx.x * 16 + c;
    float* dst; int ncol2, cl2;
    if (colg < 256)       { dst = coef + DG_OFF; ncol2 = 256;  cl2 = colg; }
    else if (colg < 512)  { dst = coef + DB_OFF; ncol2 = 256;  cl2 = colg - 256; }
    else if (colg < 1536) { dst = coef + UG_OFF; ncol2 = 1024; cl2 = colg - 512; }
    else                  { dst = coef + UB_OFF; ncol2 = 1024; cl2 = colg - 1536; }
    dst[b * ncol2 + cl2] = s;
  }
}

// ---------- build pre-swizzled bf16 weight images ----------
// image chunk = [128 n][64 k] bf16, 16B granule g at byte n*128 + ((g^(n&7))<<4)
__global__ void wimg_kernel(const float* __restrict__ Wd, const float* __restrict__ Wu,
                            char* __restrict__ ws) {
  const int bid = blockIdx.x;
  const float* src; char* dst; int C, ntile, kc;
  if (bid < 32) { src = Wd; C = 256;  ntile = bid >> 4; kc = bid & 15;
                  dst = ws + W1_BYTE + (size_t)(ntile * 16 + kc) * 16384; }
  else { int b2 = bid - 32; src = Wu; C = 1024; ntile = b2 >> 2; kc = b2 & 3;
         dst = ws + W2_BYTE + (size_t)(ntile * 4 + kc) * 16384; }
  const int t = threadIdx.x;
  const int n = t >> 1, kh = t & 1;
  const float* sp = src + (size_t)(kc * 64 + kh * 32) * C + ntile * 128 + n;
  unsigned short tmp[32];
#pragma unroll
  for (int kk = 0; kk < 32; ++kk) tmp[kk] = f2bf(sp[(size_t)kk * C]);
  char* drow = dst + n * 128;
#pragma unroll
  for (int gi = 0; gi < 4; ++gi) {
    u16x8 v;
#pragma unroll
    for (int e = 0; e < 8; ++e) v[e] = tmp[gi * 8 + e];
    int g = kh * 4 + gi;
    *(u16x8*)(drow + ((g ^ (n & 7)) << 4)) = v;
  }
}

// ---------- GEMM1: act_img = relu(dg ∘ (X @ Wd) + db ∘ rowsum(X)) ----------
// BM=64, BN=128, BK=64. 1024 blocks (4/CU), 4 waves (2m x 2n), wave tile 32x64.
// X staged RAW f32 via gl_lds with source-granule XOR pre-swizzle; cvt on read.
__global__ __launch_bounds__(256, 4)
void gemm1_kernel(const float* __restrict__ X, char* __restrict__ ws) {
  __shared__ char lds[33536];   // Xf32 [64][256B] @0 ; W bf16 [128][64] @16384 ; tail @32768
  const int tid = threadIdx.x;
  const int lane = tid & 63, wave = tid >> 6;
  const int lr = lane & 15, lq = lane >> 4;
  const int wm = wave >> 1, wn = wave & 1;

  const int raw = blockIdx.x;
  const int swz = (raw & 7) * 128 + (raw >> 3);     // 1024 % 8 == 0, bijective
  const int ntile = swz & 1, mrow = swz >> 1;
  const int row0 = mrow << 6;
  const int b = row0 >> 12;

  const float* coef = (const float*)ws;
  const char* w1img = ws + W1_BYTE + (size_t)(ntile * 16) * 16384;
  float* asump = (float*)(ws + ASUM_BYTE);

  const int srow = tid >> 4, scol = tid & 15;   // X staging: row srow+16j, granule scol
  // src pre-swizzled so LDS[r][g] = X[r][g ^ (r&15)] with linear gl_lds dest
  const float* xsrc = X + (size_t)(row0 + srow) * 1024 + ((scol ^ srow) << 2);

  int aoff[2][2][2], boff[4][2];
#pragma unroll
  for (int mf = 0; mf < 2; ++mf)
#pragma unroll
    for (int kf = 0; kf < 2; ++kf) {
      int r = wm * 32 + mf * 16 + lr;
      int g0 = kf * 8 + lq * 2;
      aoff[mf][kf][0] = r * 256 + ((g0 ^ lr) << 4);
      aoff[mf][kf][1] = r * 256 + (((g0 + 1) ^ lr) << 4);
    }
#pragma unroll
  for (int nf = 0; nf < 4; ++nf)
#pragma unroll
    for (int kf = 0; kf < 2; ++kf) {
      int n = wn * 64 + nf * 16 + lr;
      boff[nf][kf] = 16384 + n * 128 + (((kf * 4 + lq) ^ (n & 7)) << 4);
    }

  f32x4 acc[2][4] = {};
  float hacc[2] = {0.f, 0.f};

  for (int t = 0; t < 16; ++t) {
    // ---- stage (all gl_lds, single buffer) ----
#pragma unroll
    for (int j = 0; j < 4; ++j)
      gl_lds16(xsrc + (size_t)(t * 64) + (size_t)(16 * j) * 1024, lds + j * 4096 + tid * 16);
#pragma unroll
    for (int i = 0; i < 4; ++i)
      gl_lds16(w1img + (size_t)t * 16384 + i * 4096 + tid * 16,
               lds + 16384 + i * 4096 + tid * 16);
    __syncthreads();
    // ---- compute ----
#pragma unroll
    for (int kf = 0; kf < 2; ++kf) {
      s16x8 afr[2], bfr[4];
#pragma unroll
      for (int mf = 0; mf < 2; ++mf) {
        f32x4 fa0 = *(const f32x4*)(lds + aoff[mf][kf][0]);
        f32x4 fa1 = *(const f32x4*)(lds + aoff[mf][kf][1]);
        if (wn == 0)
          hacc[mf] += fa0[0] + fa0[1] + fa0[2] + fa0[3] + fa1[0] + fa1[1] + fa1[2] + fa1[3];
        u32x4 p;
        p[0] = cvt_pk(fa0[0], fa0[1]); p[1] = cvt_pk(fa0[2], fa0[3]);
        p[2] = cvt_pk(fa1[0], fa1[1]); p[3] = cvt_pk(fa1[2], fa1[3]);
        union { u32x4 u; s16x8 s; } cv; cv.u = p; afr[mf] = cv.s;
      }
#pragma unroll
      for (int nf = 0; nf < 4; ++nf) bfr[nf] = *(const s16x8*)(lds + boff[nf][kf]);
#pragma unroll
      for (int mf = 0; mf < 2; ++mf)
#pragma unroll
        for (int nf = 0; nf < 4; ++nf)
          acc[mf][nf] = __builtin_amdgcn_mfma_f32_16x16x32_bf16(afr[mf], bfr[nf], acc[mf][nf], 0, 0, 0);
    }
    __syncthreads();
  }

  // ---- epilogue ----
  float* hsumb = (float*)(lds + 32768);          // 64 f32
  float* asumb = (float*)(lds + 32768 + 256);    // 128 f32
  char* rep = lds;                                // 16 KB act repack [2 kcl][64 r][64 k]
#pragma unroll
  for (int mf = 0; mf < 2; ++mf) {
    float s = hacc[mf];
    s += __shfl_xor(s, 16); s += __shfl_xor(s, 32);
    if (wn == 0 && lq == 0) hsumb[wm * 32 + mf * 16 + lr] = s;
  }
  __syncthreads();

  float dgv[4], dbv[4];
#pragma unroll
  for (int nf = 0; nf < 4; ++nf) {
    int h = ntile * 128 + wn * 64 + nf * 16 + lr;
    dgv[nf] = coef[DG_OFF + b * 256 + h];
    dbv[nf] = coef[DB_OFF + b * 256 + h];
  }

  float asacc[2][4] = {};
#pragma unroll
  for (int nf = 0; nf < 4; ++nf) {
    int g = nf * 2 + (lr >> 3);
    char* nbase = rep + wn * 8192 + (lr & 7) * 2;
    float dg_ = dgv[nf], db_ = dbv[nf];
#pragma unroll
    for (int mf = 0; mf < 2; ++mf) {
      int rb = wm * 32 + mf * 16 + lq * 4;
#pragma unroll
      for (int j = 0; j < 4; ++j) {
        int r = rb + j;
        float v = acc[mf][nf][j] * dg_ + db_ * hsumb[r];
        v = fmaxf(v, 0.f);
        asacc[mf][j] += v;
        *(unsigned short*)(nbase + r * 128 + ((g ^ (r & 7)) << 4)) = f2bf(v);
      }
    }
  }
#pragma unroll
  for (int mf = 0; mf < 2; ++mf)
#pragma unroll
    for (int j = 0; j < 4; ++j) {
      float s = asacc[mf][j];
      s += __shfl_xor(s, 1); s += __shfl_xor(s, 2); s += __shfl_xor(s, 4); s += __shfl_xor(s, 8);
      if (lr == 0) asumb[wn * 64 + wm * 32 + mf * 16 + lq * 4 + j] = s;
    }
  __syncthreads();

  // coalesced copy-out into act image [m128][4 kc][128 r][64 k]
  const int m128 = mrow >> 1, rhalf = mrow & 1;
  char* actb = ws + ACT_BYTE + (size_t)m128 * 65536 + rhalf * 8192;
#pragma unroll
  for (int i = 0; i < 4; ++i) {
    int o = i * 4096 + tid * 16;
    int kcl = o >> 13, woff = o & 8191;
    *(u16x8*)(actb + (size_t)(ntile * 2 + kcl) * 16384 + woff) = *(const u16x8*)(rep + o);
  }
  if (tid < 64) asump[ntile * 32768 + row0 + tid] = asumb[tid] + asumb[64 + tid];
}

// ---------- GEMM2: out = ug ∘ (act @ Wu) + ub ∘ rowsum(act) + X ----------
// BM=64, BN=128, K=256 (4 steps). 4096 blocks (6/CU via 24KB LDS), single-buffered.
__global__ __launch_bounds__(256, 6)
void gemm2_kernel(const float* __restrict__ X, const char* __restrict__ ws,
                  float* __restrict__ out) {
  __shared__ char lds[24576];   // act bf16 [64][64] @0 ; W bf16 [128][64] @8192
  const int tid = threadIdx.x;
  const int lane = tid & 63, wave = tid >> 6;
  const int lr = lane & 15, lq = lane >> 4;
  const int wm = wave >> 1, wn = wave & 1;

  const int raw = blockIdx.x;
  const int swz = (raw & 7) * 512 + (raw >> 3);   // 4096 % 8 == 0, bijective
  const int nt = swz & 7, mrow = swz >> 3;
  const int row0 = mrow << 6, n0 = nt << 7;
  const int b = row0 >> 12;

  const float* coef = (const float*)ws;
  const int m128 = mrow >> 1, rhalf = mrow & 1;
  const char* aimg = ws + ACT_BYTE + (size_t)m128 * 65536 + rhalf * 8192;
  const char* wimg = ws + W2_BYTE + (size_t)(nt * 4) * 16384;
  const float* asump = (const float*)(ws + ASUM_BYTE);

  int aoff[2][2], boff[4][2];
#pragma unroll
  for (int mf = 0; mf < 2; ++mf)
#pragma unroll
    for (int kf = 0; kf < 2; ++kf) {
      int r = wm * 32 + mf * 16 + lr;
      aoff[mf][kf] = r * 128 + (((kf * 4 + lq) ^ (r & 7)) << 4);
    }
#pragma unroll
  for (int nf = 0; nf < 4; ++nf)
#pragma unroll
    for (int kf = 0; kf < 2; ++kf) {
      int n = wn * 64 + nf * 16 + lr;
      boff[nf][kf] = 8192 + n * 128 + (((kf * 4 + lq) ^ (n & 7)) << 4);
    }

  f32x4 acc[2][4] = {};

  for (int t = 0; t < 4; ++t) {
#pragma unroll
    for (int i = 0; i < 2; ++i)
      gl_lds16(aimg + (size_t)t * 16384 + i * 4096 + tid * 16, lds + i * 4096 + tid * 16);
#pragma unroll
    for (int i = 0; i < 4; ++i)
      gl_lds16(wimg + (size_t)t * 16384 + i * 4096 + tid * 16,
               lds + 8192 + i * 4096 + tid * 16);
    __syncthreads();
#pragma unroll
    for (int kf = 0; kf < 2; ++kf) {
      s16x8 afr[2], bfr[4];
#pragma unroll
      for (int mf = 0; mf < 2; ++mf) afr[mf] = *(const s16x8*)(lds + aoff[mf][kf]);
#pragma unroll
      for (int nf = 0; nf < 4; ++nf) bfr[nf] = *(const s16x8*)(lds + boff[nf][kf]);
#pragma unroll
      for (int mf = 0; mf < 2; ++mf)
#pragma unroll
        for (int nf = 0; nf < 4; ++nf)
          acc[mf][nf] = __builtin_amdgcn_mfma_f32_16x16x32_bf16(afr[mf], bfr[nf], acc[mf][nf], 0, 0, 0);
    }
    __syncthreads();
  }

  // ---- epilogue: direct stores (16-lane x 64B = full cache lines) ----
  float ugv[4], ubv[4];
#pragma unroll
  for (int nf = 0; nf < 4; ++nf) {
    int d = n0 + wn * 64 + nf * 16 + lr;
    ugv[nf] = coef[UG_OFF + b * 1024 + d];
    ubv[nf] = coef[UB_OFF + b * 1024 + d];
  }
#pragma unroll
  for (int mf = 0; mf < 2; ++mf) {
#pragma unroll
    for (int j = 0; j < 4; ++j) {
      int r = row0 + wm * 32 + mf * 16 + lq * 4 + j;
      float as = asump[r] + asump[32768 + r];
      size_t rowb = (size_t)r * 1024;
#pragma unroll
      for (int nf = 0; nf < 4; ++nf) {
        size_t gi = rowb + n0 + wn * 64 + nf * 16 + lr;
        out[gi] = acc[mf][nf][j] * ugv[nf] + ubv[nf] * as + X[gi];
      }
    }
  }
}

extern "C" void kernel_launch(void* const* d_in, const int* in_sizes, int n_in,
                              void* d_out, int out_size, void* d_ws, size_t ws_size,
                              hipStream_t stream) {
  const float* hidden       = (const float*)d_in[0];
  const float* conditions   = (const float*)d_in[1];
  const float* down_project = (const float*)d_in[2];
  const float* down_gamma   = (const float*)d_in[3];
  const float* down_beta    = (const float*)d_in[4];
  const float* up_project   = (const float*)d_in[5];
  const float* up_gamma     = (const float*)d_in[6];
  const float* up_beta      = (const float*)d_in[7];
  float* out = (float*)d_out;
  char* ws = (char*)d_ws;

  coef_kernel<<<160, 256, 0, stream>>>(conditions, down_gamma, down_beta, up_gamma, up_beta,
                                       (float*)ws);
  wimg_kernel<<<64, 256, 0, stream>>>(down_project, up_project, ws);
  gemm1_kernel<<<1024, 256, 0, stream>>>(hidden, ws);
  gemm2_kernel<<<4096, 256, 0, stream>>>(hidden, ws, out);
}

// Round 6
// 100.441 us; speedup vs baseline: 1.1616x; 1.0066x over previous
//
#include <hip/hip_runtime.h>
#include <hip/hip_bf16.h>

typedef __attribute__((ext_vector_type(4))) float f32x4;
typedef __attribute__((ext_vector_type(8))) short s16x8;
typedef __attribute__((ext_vector_type(8))) unsigned short u16x8;
typedef __attribute__((ext_vector_type(4))) unsigned int u32x4;

#define DEVFN static __device__ __forceinline__

DEVFN unsigned short f2bf(float f) {
  union { float f; unsigned int u; } v; v.f = f;
  unsigned int u = v.u;
  u += 0x7fffu + ((u >> 16) & 1u);   // RNE
  return (unsigned short)(u >> 16);
}

DEVFN unsigned int cvt_pk(float a, float b) {
  __hip_bfloat162 h = __float22bfloat162_rn(make_float2(a, b));
  union { __hip_bfloat162 h; unsigned int u; } v; v.h = h; return v.u;
}

DEVFN void gl_lds16(const void* g, void* l) {
  __builtin_amdgcn_global_load_lds((__attribute__((address_space(1))) void*)g,
                                   (__attribute__((address_space(3))) void*)l, 16, 0, 0);
}

// ws layout (bytes)
#define DG_OFF 0
#define DB_OFF 2048
#define UG_OFF 4096
#define UB_OFF 12288
#define W1_BYTE   81920      // [2 ntile][16 kc][128 n][64 k] bf16 swizzled  (512 KB)
#define W2_BYTE   606208     // [8 ntile][4 kc][128 n][64 k] bf16 swizzled   (512 KB)
#define ASUM_BYTE 1130496    // float asum_part[2][32768]                    (256 KB)
#define ACT_BYTE  1392640    // [256 mtile][4 kc][128 r][64 k] bf16 swizzled (16 MB)

// ---------- merged prep: wimg (blocks 0..63) + coef (blocks 64..223) ----------
__global__ void prep_kernel(const float* __restrict__ cond,
                            const float* __restrict__ dgm, const float* __restrict__ dbt,
                            const float* __restrict__ ugm, const float* __restrict__ ubt,
                            const float* __restrict__ Wd, const float* __restrict__ Wu,
                            char* __restrict__ ws) {
  __shared__ float lc[4096];
  __shared__ float red[2048];
  const int t = threadIdx.x;

  if (blockIdx.x < 64) {
    // ----- weight image build -----
    const int bid = blockIdx.x;
    const float* src; char* dst; int C, ntile, kc;
    if (bid < 32) { src = Wd; C = 256;  ntile = bid >> 4; kc = bid & 15;
                    dst = ws + W1_BYTE + (size_t)(ntile * 16 + kc) * 16384; }
    else { int b2 = bid - 32; src = Wu; C = 1024; ntile = b2 >> 2; kc = b2 & 3;
           dst = ws + W2_BYTE + (size_t)(ntile * 4 + kc) * 16384; }
    const int n = t >> 1, kh = t & 1;
    const float* sp = src + (size_t)(kc * 64 + kh * 32) * C + ntile * 128 + n;
    unsigned short tmp[32];
#pragma unroll
    for (int kk = 0; kk < 32; ++kk) tmp[kk] = f2bf(sp[(size_t)kk * C]);
    char* drow = dst + n * 128;
#pragma unroll
    for (int gi = 0; gi < 4; ++gi) {
      u16x8 v;
#pragma unroll
      for (int e = 0; e < 8; ++e) v[e] = tmp[gi * 8 + e];
      int g = kh * 4 + gi;
      *(u16x8*)(drow + ((g ^ (n & 7)) << 4)) = v;
    }
    return;
  }

  // ----- coefficient GEMMs: conditions[8,512] @ {gamma,beta} -----
  float* coef = (float*)ws;
#pragma unroll
  for (int i = 0; i < 16; ++i) lc[t + i * 256] = cond[t + i * 256];
  __syncthreads();
  const int bid2 = blockIdx.x - 64;
  const int col = bid2 * 16 + (t & 15);
  const int ks = t >> 4;
  const float* src; int ncol, cl;
  if (col < 256)       { src = dgm; ncol = 256;  cl = col; }
  else if (col < 512)  { src = dbt; ncol = 256;  cl = col - 256; }
  else if (col < 1536) { src = ugm; ncol = 1024; cl = col - 512; }
  else                 { src = ubt; ncol = 1024; cl = col - 1536; }
  float acc[8] = {};
  for (int k = ks * 32; k < ks * 32 + 32; ++k) {
    float g = src[(size_t)k * ncol + cl];
#pragma unroll
    for (int b = 0; b < 8; ++b) acc[b] = fmaf(lc[b * 512 + k], g, acc[b]);
  }
#pragma unroll
  for (int b = 0; b < 8; ++b) red[(ks * 16 + (t & 15)) * 8 + b] = acc[b];
  __syncthreads();
  if (t < 128) {
    int c = t >> 3, b = t & 7;
    float s = 0.f;
#pragma unroll
    for (int k2 = 0; k2 < 16; ++k2) s += red[(k2 * 16 + c) * 8 + b];
    int colg = bid2 * 16 + c;
    float* dst; int ncol2, cl2;
    if (colg < 256)       { dst = coef + DG_OFF; ncol2 = 256;  cl2 = colg; }
    else if (colg < 512)  { dst = coef + DB_OFF; ncol2 = 256;  cl2 = colg - 256; }
    else if (colg < 1536) { dst = coef + UG_OFF; ncol2 = 1024; cl2 = colg - 512; }
    else                  { dst = coef + UB_OFF; ncol2 = 1024; cl2 = colg - 1536; }
    dst[b * ncol2 + cl2] = s;
  }
}

// ---------- GEMM1: act_img = relu(dg ∘ (X @ Wd) + db ∘ rowsum(X)) ----------
// BM=64, BN=128, BK=64, T=16. Double-buffered LDS + counted vmcnt + raw barriers.
// X staged RAW f32 via gl_lds with source-granule XOR pre-swizzle; cvt on read.
__global__ __launch_bounds__(256, 2)
void gemm1_kernel(const float* __restrict__ X, char* __restrict__ ws) {
  __shared__ char lds[66304];   // X0@0 X1@16K | W0@32K W1@48K | sums@64K
  const int tid = threadIdx.x;
  const int lane = tid & 63, wave = tid >> 6;
  const int lr = lane & 15, lq = lane >> 4;
  const int wm = wave >> 1, wn = wave & 1;

  const int raw = blockIdx.x;
  const int swz = (raw & 7) * 128 + (raw >> 3);     // 1024 % 8 == 0, bijective
  const int ntile = swz & 1, mrow = swz >> 1;
  const int row0 = mrow << 6;
  const int b = row0 >> 12;

  const float* coef = (const float*)ws;
  const char* w1img = ws + W1_BYTE + (size_t)(ntile * 16) * 16384;
  float* asump = (float*)(ws + ASUM_BYTE);

  const int srow = tid >> 4, scol = tid & 15;
  // src pre-swizzled so LDS[r][g] = X[r][4*(g ^ (r&15))] with linear gl_lds dest
  const float* xsrc = X + (size_t)(row0 + srow) * 1024 + ((scol ^ srow) << 2);

  int aoff[2][2][2], boff[4][2];
#pragma unroll
  for (int mf = 0; mf < 2; ++mf)
#pragma unroll
    for (int kf = 0; kf < 2; ++kf) {
      int r = wm * 32 + mf * 16 + lr;
      int g0 = kf * 8 + lq * 2;
      aoff[mf][kf][0] = r * 256 + ((g0 ^ lr) << 4);
      aoff[mf][kf][1] = r * 256 + (((g0 + 1) ^ lr) << 4);
    }
#pragma unroll
  for (int nf = 0; nf < 4; ++nf)
#pragma unroll
    for (int kf = 0; kf < 2; ++kf) {
      int n = wn * 64 + nf * 16 + lr;
      boff[nf][kf] = 32768 + n * 128 + (((kf * 4 + lq) ^ (n & 7)) << 4);
    }

  f32x4 acc[2][4] = {};
  float hacc[2] = {0.f, 0.f};

  // stage tile s into buffer (s&1): 4 X gl_lds + 4 W gl_lds per thread
#define G1_STAGE(s)                                                              \
  {                                                                              \
    char* xb = lds + ((s) & 1) * 16384;                                          \
    char* wb = lds + 32768 + ((s) & 1) * 16384;                                  \
    _Pragma("unroll")                                                            \
    for (int j = 0; j < 4; ++j)                                                  \
      gl_lds16(xsrc + (size_t)((s) * 64) + (size_t)(16 * j) * 1024,              \
               xb + j * 4096 + tid * 16);                                        \
    _Pragma("unroll")                                                            \
    for (int i = 0; i < 4; ++i)                                                  \
      gl_lds16(w1img + (size_t)(s) * 16384 + i * 4096 + tid * 16,                \
               wb + i * 4096 + tid * 16);                                        \
  }

  G1_STAGE(0);
  G1_STAGE(1);

  for (int t = 0; t < 16; ++t) {
    if (t < 15) asm volatile("s_waitcnt vmcnt(8)" ::: "memory");
    else        asm volatile("s_waitcnt vmcnt(0)" ::: "memory");
    __builtin_amdgcn_sched_barrier(0);
    __builtin_amdgcn_s_barrier();
    __builtin_amdgcn_sched_barrier(0);

    const char* Xc = lds + (t & 1) * 16384;
    const char* Wc = lds + (t & 1) * 16384;   // boff already includes +32768
#pragma unroll
    for (int kf = 0; kf < 2; ++kf) {
      s16x8 afr[2], bfr[4];
#pragma unroll
      for (int mf = 0; mf < 2; ++mf) {
        f32x4 fa0 = *(const f32x4*)(Xc + aoff[mf][kf][0]);
        f32x4 fa1 = *(const f32x4*)(Xc + aoff[mf][kf][1]);
        if (wn == 0)
          hacc[mf] += fa0[0] + fa0[1] + fa0[2] + fa0[3] + fa1[0] + fa1[1] + fa1[2] + fa1[3];
        u32x4 p;
        p[0] = cvt_pk(fa0[0], fa0[1]); p[1] = cvt_pk(fa0[2], fa0[3]);
        p[2] = cvt_pk(fa1[0], fa1[1]); p[3] = cvt_pk(fa1[2], fa1[3]);
        union { u32x4 u; s16x8 s; } cv; cv.u = p; afr[mf] = cv.s;
      }
#pragma unroll
      for (int nf = 0; nf < 4; ++nf) bfr[nf] = *(const s16x8*)(Wc + boff[nf][kf]);
#pragma unroll
      for (int mf = 0; mf < 2; ++mf)
#pragma unroll
        for (int nf = 0; nf < 4; ++nf)
          acc[mf][nf] = __builtin_amdgcn_mfma_f32_16x16x32_bf16(afr[mf], bfr[nf], acc[mf][nf], 0, 0, 0);
    }

    asm volatile("s_waitcnt lgkmcnt(0)" ::: "memory");
    __builtin_amdgcn_sched_barrier(0);
    __builtin_amdgcn_s_barrier();
    __builtin_amdgcn_sched_barrier(0);
    if (t + 2 < 16) G1_STAGE(t + 2);
  }

  // ---- epilogue ----
  float* hsumb = (float*)(lds + 65536);          // 64 f32
  float* asumb = (float*)(lds + 65536 + 256);    // 128 f32
  char* rep = lds;                               // 16 KB act repack [2 kcl][64 r][64 k]
#pragma unroll
  for (int mf = 0; mf < 2; ++mf) {
    float s = hacc[mf];
    s += __shfl_xor(s, 16); s += __shfl_xor(s, 32);
    if (wn == 0 && lq == 0) hsumb[wm * 32 + mf * 16 + lr] = s;
  }
  __syncthreads();

  float dgv[4], dbv[4];
#pragma unroll
  for (int nf = 0; nf < 4; ++nf) {
    int h = ntile * 128 + wn * 64 + nf * 16 + lr;
    dgv[nf] = coef[DG_OFF + b * 256 + h];
    dbv[nf] = coef[DB_OFF + b * 256 + h];
  }

  float asacc[2][4] = {};
#pragma unroll
  for (int nf = 0; nf < 4; ++nf) {
    int g = nf * 2 + (lr >> 3);
    char* nbase = rep + wn * 8192 + (lr & 7) * 2;
    float dg_ = dgv[nf], db_ = dbv[nf];
#pragma unroll
    for (int mf = 0; mf < 2; ++mf) {
      int rb = wm * 32 + mf * 16 + lq * 4;
#pragma unroll
      for (int j = 0; j < 4; ++j) {
        int r = rb + j;
        float v = acc[mf][nf][j] * dg_ + db_ * hsumb[r];
        v = fmaxf(v, 0.f);
        asacc[mf][j] += v;
        *(unsigned short*)(nbase + r * 128 + ((g ^ (r & 7)) << 4)) = f2bf(v);
      }
    }
  }
#pragma unroll
  for (int mf = 0; mf < 2; ++mf)
#pragma unroll
    for (int j = 0; j < 4; ++j) {
      float s = asacc[mf][j];
      s += __shfl_xor(s, 1); s += __shfl_xor(s, 2); s += __shfl_xor(s, 4); s += __shfl_xor(s, 8);
      if (lr == 0) asumb[wn * 64 + wm * 32 + mf * 16 + lq * 4 + j] = s;
    }
  __syncthreads();

  // coalesced copy-out into act image [m128][4 kc][128 r][64 k]
  const int m128 = mrow >> 1, rhalf = mrow & 1;
  char* actb = ws + ACT_BYTE + (size_t)m128 * 65536 + rhalf * 8192;
#pragma unroll
  for (int i = 0; i < 4; ++i) {
    int o = i * 4096 + tid * 16;
    int kcl = o >> 13, woff = o & 8191;
    *(u16x8*)(actb + (size_t)(ntile * 2 + kcl) * 16384 + woff) = *(const u16x8*)(rep + o);
  }
  if (tid < 64) asump[ntile * 32768 + row0 + tid] = asumb[tid] + asumb[64 + tid];
}

// ---------- GEMM2: out = ug ∘ (act @ Wu) + ub ∘ rowsum(act) + X ----------
// BM=64, BN=128, T=4 (K=256). Dbuf + counted vmcnt + raw barriers; direct stores.
__global__ __launch_bounds__(256, 3)
void gemm2_kernel(const float* __restrict__ X, const char* __restrict__ ws,
                  float* __restrict__ out) {
  __shared__ char lds[49152];   // A0@0 A1@8K | W0@16K W1@32K
  const int tid = threadIdx.x;
  const int lane = tid & 63, wave = tid >> 6;
  const int lr = lane & 15, lq = lane >> 4;
  const int wm = wave >> 1, wn = wave & 1;

  const int raw = blockIdx.x;
  const int swz = (raw & 7) * 512 + (raw >> 3);   // 4096 % 8 == 0, bijective
  const int nt = swz & 7, mrow = swz >> 3;
  const int row0 = mrow << 6, n0 = nt << 7;
  const int b = row0 >> 12;

  const float* coef = (const float*)ws;
  const int m128 = mrow >> 1, rhalf = mrow & 1;
  const char* aimg = ws + ACT_BYTE + (size_t)m128 * 65536 + rhalf * 8192;
  const char* wimg = ws + W2_BYTE + (size_t)(nt * 4) * 16384;
  const float* asump = (const float*)(ws + ASUM_BYTE);

  int aoff[2][2], boff[4][2];
#pragma unroll
  for (int mf = 0; mf < 2; ++mf)
#pragma unroll
    for (int kf = 0; kf < 2; ++kf) {
      int r = wm * 32 + mf * 16 + lr;
      aoff[mf][kf] = r * 128 + (((kf * 4 + lq) ^ (r & 7)) << 4);
    }
#pragma unroll
  for (int nf = 0; nf < 4; ++nf)
#pragma unroll
    for (int kf = 0; kf < 2; ++kf) {
      int n = wn * 64 + nf * 16 + lr;
      boff[nf][kf] = 16384 + n * 128 + (((kf * 4 + lq) ^ (n & 7)) << 4);
    }

  f32x4 acc[2][4] = {};

#define G2_STAGE(s)                                                              \
  {                                                                              \
    char* ab = lds + ((s) & 1) * 8192;                                           \
    char* wb = lds + 16384 + ((s) & 1) * 16384;                                  \
    _Pragma("unroll")                                                            \
    for (int i = 0; i < 2; ++i)                                                  \
      gl_lds16(aimg + (size_t)(s) * 16384 + i * 4096 + tid * 16,                 \
               ab + i * 4096 + tid * 16);                                        \
    _Pragma("unroll")                                                            \
    for (int i = 0; i < 4; ++i)                                                  \
      gl_lds16(wimg + (size_t)(s) * 16384 + i * 4096 + tid * 16,                 \
               wb + i * 4096 + tid * 16);                                        \
  }

  G2_STAGE(0);
  G2_STAGE(1);

  for (int t = 0; t < 4; ++t) {
    if (t < 3) asm volatile("s_waitcnt vmcnt(6)" ::: "memory");
    else       asm volatile("s_waitcnt vmcnt(0)" ::: "memory");
    __builtin_amdgcn_sched_barrier(0);
    __builtin_amdgcn_s_barrier();
    __builtin_amdgcn_sched_barrier(0);

    const char* Ac = lds + (t & 1) * 8192;
    const char* Wc = lds + (t & 1) * 16384;   // boff already includes +16384
#pragma unroll
    for (int kf = 0; kf < 2; ++kf) {
      s16x8 afr[2], bfr[4];
#pragma unroll
      for (int mf = 0; mf < 2; ++mf) afr[mf] = *(const s16x8*)(Ac + aoff[mf][kf]);
#pragma unroll
      for (int nf = 0; nf < 4; ++nf) bfr[nf] = *(const s16x8*)(Wc + boff[nf][kf]);
#pragma unroll
      for (int mf = 0; mf < 2; ++mf)
#pragma unroll
        for (int nf = 0; nf < 4; ++nf)
          acc[mf][nf] = __builtin_amdgcn_mfma_f32_16x16x32_bf16(afr[mf], bfr[nf], acc[mf][nf], 0, 0, 0);
    }

    asm volatile("s_waitcnt lgkmcnt(0)" ::: "memory");
    __builtin_amdgcn_sched_barrier(0);
    __builtin_amdgcn_s_barrier();
    __builtin_amdgcn_sched_barrier(0);
    if (t + 2 < 4) G2_STAGE(t + 2);
  }

  // ---- epilogue: direct stores (16-lane x 64B = full cache lines) ----
  float ugv[4], ubv[4];
#pragma unroll
  for (int nf = 0; nf < 4; ++nf) {
    int d = n0 + wn * 64 + nf * 16 + lr;
    ugv[nf] = coef[UG_OFF + b * 1024 + d];
    ubv[nf] = coef[UB_OFF + b * 1024 + d];
  }
#pragma unroll
  for (int mf = 0; mf < 2; ++mf) {
#pragma unroll
    for (int j = 0; j < 4; ++j) {
      int r = row0 + wm * 32 + mf * 16 + lq * 4 + j;
      float as = asump[r] + asump[32768 + r];
      size_t rowb = (size_t)r * 1024;
#pragma unroll
      for (int nf = 0; nf < 4; ++nf) {
        size_t gi = rowb + n0 + wn * 64 + nf * 16 + lr;
        out[gi] = acc[mf][nf][j] * ugv[nf] + ubv[nf] * as + X[gi];
      }
    }
  }
}

extern "C" void kernel_launch(void* const* d_in, const int* in_sizes, int n_in,
                              void* d_out, int out_size, void* d_ws, size_t ws_size,
                              hipStream_t stream) {
  const float* hidden       = (const float*)d_in[0];
  const float* conditions   = (const float*)d_in[1];
  const float* down_project = (const float*)d_in[2];
  const float* down_gamma   = (const float*)d_in[3];
  const float* down_beta    = (const float*)d_in[4];
  const float* up_project   = (const float*)d_in[5];
  const float* up_gamma     = (const float*)d_in[6];
  const float* up_beta      = (const float*)d_in[7];
  float* out = (float*)d_out;
  char* ws = (char*)d_ws;

  prep_kernel<<<224, 256, 0, stream>>>(conditions, down_gamma, down_beta, up_gamma, up_beta,
                                       down_project, up_project, ws);
  gemm1_kernel<<<1024, 256, 0, stream>>>(hidden, ws);
  gemm2_kernel<<<4096, 256, 0, stream>>>(hidden, ws, out);
}

// Round 7
// 96.723 us; speedup vs baseline: 1.2063x; 1.0384x over previous
//
#include <hip/hip_runtime.h>
#include <hip/hip_bf16.h>

typedef __attribute__((ext_vector_type(4))) float f32x4;
typedef __attribute__((ext_vector_type(8))) short s16x8;
typedef __attribute__((ext_vector_type(8))) unsigned short u16x8;
typedef __attribute__((ext_vector_type(4))) unsigned int u32x4;

#define DEVFN static __device__ __forceinline__

DEVFN unsigned short f2bf(float f) {
  union { float f; unsigned int u; } v; v.f = f;
  unsigned int u = v.u;
  u += 0x7fffu + ((u >> 16) & 1u);   // RNE
  return (unsigned short)(u >> 16);
}

DEVFN unsigned int cvt_pk(float a, float b) {
  __hip_bfloat162 h = __float22bfloat162_rn(make_float2(a, b));
  union { __hip_bfloat162 h; unsigned int u; } v; v.h = h; return v.u;
}

DEVFN void gl_lds16(const void* g, void* l) {
  __builtin_amdgcn_global_load_lds((__attribute__((address_space(1))) void*)g,
                                   (__attribute__((address_space(3))) void*)l, 16, 0, 0);
}

// ws layout (bytes)
#define DG_OFF 0
#define DB_OFF 2048
#define UG_OFF 4096
#define UB_OFF 12288
#define W1_BYTE 81920        // [16 kc][2 ntile][128 n][64 k] bf16 swizzled (512 KB)
#define W2_BYTE 606208       // [8 nt][4 kc][128 n][64 k] bf16 swizzled    (512 KB)

// ---------- merged prep: wimg (blocks 0..63) + coef (blocks 64..223) ----------
__global__ void prep_kernel(const float* __restrict__ cond,
                            const float* __restrict__ dgm, const float* __restrict__ dbt,
                            const float* __restrict__ ugm, const float* __restrict__ ubt,
                            const float* __restrict__ Wd, const float* __restrict__ Wu,
                            char* __restrict__ ws) {
  __shared__ float lc[4096];
  __shared__ float red[2048];
  const int t = threadIdx.x;

  if (blockIdx.x < 64) {
    const int bid = blockIdx.x;
    const float* src; char* dst; int C, ntile, kc;
    if (bid < 32) { src = Wd; C = 256;  ntile = bid >> 4; kc = bid & 15;
                    dst = ws + W1_BYTE + (size_t)(kc * 2 + ntile) * 16384; }
    else { int b2 = bid - 32; src = Wu; C = 1024; ntile = b2 >> 2; kc = b2 & 3;
           dst = ws + W2_BYTE + (size_t)(ntile * 4 + kc) * 16384; }
    const int n = t >> 1, kh = t & 1;
    const float* sp = src + (size_t)(kc * 64 + kh * 32) * C + ntile * 128 + n;
    unsigned short tmp[32];
#pragma unroll
    for (int kk = 0; kk < 32; ++kk) tmp[kk] = f2bf(sp[(size_t)kk * C]);
    char* drow = dst + n * 128;
#pragma unroll
    for (int gi = 0; gi < 4; ++gi) {
      u16x8 v;
#pragma unroll
      for (int e = 0; e < 8; ++e) v[e] = tmp[gi * 8 + e];
      int g = kh * 4 + gi;
      *(u16x8*)(drow + ((g ^ (n & 7)) << 4)) = v;
    }
    return;
  }

  float* coef = (float*)ws;
#pragma unroll
  for (int i = 0; i < 16; ++i) lc[t + i * 256] = cond[t + i * 256];
  __syncthreads();
  const int bid2 = blockIdx.x - 64;
  const int col = bid2 * 16 + (t & 15);
  const int ks = t >> 4;
  const float* src; int ncol, cl;
  if (col < 256)       { src = dgm; ncol = 256;  cl = col; }
  else if (col < 512)  { src = dbt; ncol = 256;  cl = col - 256; }
  else if (col < 1536) { src = ugm; ncol = 1024; cl = col - 512; }
  else                 { src = ubt; ncol = 1024; cl = col - 1536; }
  float acc[8] = {};
  for (int k = ks * 32; k < ks * 32 + 32; ++k) {
    float g = src[(size_t)k * ncol + cl];
#pragma unroll
    for (int b = 0; b < 8; ++b) acc[b] = fmaf(lc[b * 512 + k], g, acc[b]);
  }
#pragma unroll
  for (int b = 0; b < 8; ++b) red[(ks * 16 + (t & 15)) * 8 + b] = acc[b];
  __syncthreads();
  if (t < 128) {
    int c = t >> 3, b = t & 7;
    float s = 0.f;
#pragma unroll
    for (int k2 = 0; k2 < 16; ++k2) s += red[(k2 * 16 + c) * 8 + b];
    int colg = bid2 * 16 + c;
    float* dst; int ncol2, cl2;
    if (colg < 256)       { dst = coef + DG_OFF; ncol2 = 256;  cl2 = colg; }
    else if (colg < 512)  { dst = coef + DB_OFF; ncol2 = 256;  cl2 = colg - 256; }
    else if (colg < 1536) { dst = coef + UG_OFF; ncol2 = 1024; cl2 = colg - 512; }
    else                  { dst = coef + UB_OFF; ncol2 = 1024; cl2 = colg - 1536; }
    dst[b * ncol2 + cl2] = s;
  }
}

// ---------- fused kernel: act stays in LDS ----------
// 256 blocks x 512 threads (8 waves, 2m x 4n), 128 rows per block, 1 block/CU.
// LDS 160 KiB: act[4 kc][128 r][64 k] bf16 @0 (64K) | X f32 dbuf @64K (2x32K) | W @128K (32K)
__global__ __launch_bounds__(512, 1)
void fused_kernel(const float* __restrict__ X, char* __restrict__ ws,
                  float* __restrict__ out) {
  __shared__ char lds[163840];
  const int tid = threadIdx.x;
  const int lane = tid & 63, wave = tid >> 6;
  const int lr = lane & 15, lq = lane >> 4;
  const int wm = wave >> 2, wn = wave & 3;   // 2m x 4n

  const int m0 = blockIdx.x;
  const int row0 = m0 << 7;
  const int b = m0 >> 5;

  const float* coef = (const float*)ws;
  const char* w1 = ws + W1_BYTE;
  const char* w2 = ws + W2_BYTE;

  // ===== phase 1: X @ Wd =====
  const int srow = tid >> 4, sg = tid & 15;
  const float* xsrc = X + (size_t)(row0 + srow) * 1024 + ((sg ^ (srow & 15)) << 2);

  int aoff[4][2][2], boff[4][2];
#pragma unroll
  for (int mf = 0; mf < 4; ++mf)
#pragma unroll
    for (int kf = 0; kf < 2; ++kf) {
      int r = wm * 64 + mf * 16 + lr;
      int g0 = kf * 8 + lq * 2;
      aoff[mf][kf][0] = r * 256 + ((g0 ^ (r & 15)) << 4);
      aoff[mf][kf][1] = r * 256 + (((g0 + 1) ^ (r & 15)) << 4);
    }
#pragma unroll
  for (int nf = 0; nf < 4; ++nf)
#pragma unroll
    for (int kf = 0; kf < 2; ++kf) {
      int n = wn * 64 + nf * 16 + lr;
      boff[nf][kf] = 131072 + (n >> 7) * 16384 + (n & 127) * 128 +
                     (((kf * 4 + lq) ^ (n & 7)) << 4);
    }

  f32x4 acc1[4][4] = {};
  float hacc[4] = {};

#define STAGE_X(t)                                                               \
  { char* xb = lds + 65536 + ((t) & 1) * 32768;                                  \
    _Pragma("unroll")                                                            \
    for (int i = 0; i < 4; ++i)                                                  \
      gl_lds16(xsrc + (size_t)((t) * 64) + (size_t)(i * 32) * 1024,              \
               xb + i * 8192 + tid * 16); }
#define STAGE_W1(t)                                                              \
  { _Pragma("unroll")                                                            \
    for (int i = 0; i < 4; ++i)                                                  \
      gl_lds16(w1 + (size_t)(t) * 32768 + i * 8192 + tid * 16,                   \
               lds + 131072 + i * 8192 + tid * 16); }

  STAGE_X(0); STAGE_X(1); STAGE_W1(0);
  asm volatile("s_waitcnt vmcnt(0)" ::: "memory");
  __builtin_amdgcn_sched_barrier(0);
  __builtin_amdgcn_s_barrier();
  __builtin_amdgcn_sched_barrier(0);

  for (int t = 0; t < 16; ++t) {
    const char* Xc = lds + 65536 + (t & 1) * 32768;
#pragma unroll
    for (int kf = 0; kf < 2; ++kf) {
      s16x8 afr[4], bfr[4];
#pragma unroll
      for (int mf = 0; mf < 4; ++mf) {
        f32x4 fa0 = *(const f32x4*)(Xc + aoff[mf][kf][0]);
        f32x4 fa1 = *(const f32x4*)(Xc + aoff[mf][kf][1]);
        if (wn == 0)
          hacc[mf] += fa0[0] + fa0[1] + fa0[2] + fa0[3] + fa1[0] + fa1[1] + fa1[2] + fa1[3];
        u32x4 p;
        p[0] = cvt_pk(fa0[0], fa0[1]); p[1] = cvt_pk(fa0[2], fa0[3]);
        p[2] = cvt_pk(fa1[0], fa1[1]); p[3] = cvt_pk(fa1[2], fa1[3]);
        union { u32x4 u; s16x8 s; } cv; cv.u = p; afr[mf] = cv.s;
      }
#pragma unroll
      for (int nf = 0; nf < 4; ++nf) bfr[nf] = *(const s16x8*)(lds + boff[nf][kf]);
#pragma unroll
      for (int mf = 0; mf < 4; ++mf)
#pragma unroll
        for (int nf = 0; nf < 4; ++nf)
          acc1[mf][nf] = __builtin_amdgcn_mfma_f32_16x16x32_bf16(afr[mf], bfr[nf], acc1[mf][nf], 0, 0, 0);
    }
    asm volatile("s_waitcnt lgkmcnt(0)" ::: "memory");
    __builtin_amdgcn_sched_barrier(0);
    __builtin_amdgcn_s_barrier();
    __builtin_amdgcn_sched_barrier(0);
    if (t < 15) {
      STAGE_W1(t + 1);
      if (t + 2 < 16) { STAGE_X(t + 2); asm volatile("s_waitcnt vmcnt(4)" ::: "memory"); }
      else            { asm volatile("s_waitcnt vmcnt(0)" ::: "memory"); }
      __builtin_amdgcn_sched_barrier(0);
      __builtin_amdgcn_s_barrier();
      __builtin_amdgcn_sched_barrier(0);
    }
  }

  // ===== phase-1 epilogue: hsum, modulate+relu -> act LDS, asum =====
  float* hsumb = (float*)(lds + 65536);           // 128 f32
  float* asp   = (float*)(lds + 65536 + 512);     // [4][128] f32
  if (wn == 0) {
#pragma unroll
    for (int mf = 0; mf < 4; ++mf) {
      float s = hacc[mf];
      s += __shfl_xor(s, 16); s += __shfl_xor(s, 32);
      if (lq == 0) hsumb[wm * 64 + mf * 16 + lr] = s;
    }
  }
  __syncthreads();

  float dgv[4], dbv[4];
#pragma unroll
  for (int nf = 0; nf < 4; ++nf) {
    int h = wn * 64 + nf * 16 + lr;
    dgv[nf] = coef[DG_OFF + b * 256 + h];
    dbv[nf] = coef[DB_OFF + b * 256 + h];
  }

  float asacc[4][4] = {};
#pragma unroll
  for (int nf = 0; nf < 4; ++nf) {
    int g = nf * 2 + (lr >> 3);
    char* nbase = lds + wn * 16384 + (lr & 7) * 2;   // act chunk kc = wn
    float dg_ = dgv[nf], db_ = dbv[nf];
#pragma unroll
    for (int mf = 0; mf < 4; ++mf) {
      int rb = wm * 64 + mf * 16 + lq * 4;
#pragma unroll
      for (int j = 0; j < 4; ++j) {
        int r = rb + j;
        float v = acc1[mf][nf][j] * dg_ + db_ * hsumb[r];
        v = fmaxf(v, 0.f);
        asacc[mf][j] += v;
        *(unsigned short*)(nbase + r * 128 + ((g ^ (r & 7)) << 4)) = f2bf(v);
      }
    }
  }
#pragma unroll
  for (int mf = 0; mf < 4; ++mf)
#pragma unroll
    for (int j = 0; j < 4; ++j) {
      float s = asacc[mf][j];
      s += __shfl_xor(s, 1); s += __shfl_xor(s, 2); s += __shfl_xor(s, 4); s += __shfl_xor(s, 8);
      if (lr == 0) asp[wn * 128 + wm * 64 + mf * 16 + lq * 4 + j] = s;
    }
  __syncthreads();

  // ===== phase-2 preloads =====
  float asv[4][4];
#pragma unroll
  for (int mf = 0; mf < 4; ++mf)
#pragma unroll
    for (int j = 0; j < 4; ++j) {
      int r = wm * 64 + mf * 16 + lq * 4 + j;
      asv[mf][j] = asp[r] + asp[128 + r] + asp[256 + r] + asp[384 + r];
    }
  float ugA[8][2], ubA[8][2];
#pragma unroll
  for (int nt = 0; nt < 8; ++nt)
#pragma unroll
    for (int nf = 0; nf < 2; ++nf) {
      int d = nt * 128 + wn * 32 + nf * 16 + lr;
      ugA[nt][nf] = coef[UG_OFF + b * 1024 + d];
      ubA[nt][nf] = coef[UB_OFF + b * 1024 + d];
    }

  int a2off[4][2], b2off[2][2];
#pragma unroll
  for (int mf = 0; mf < 4; ++mf)
#pragma unroll
    for (int kf = 0; kf < 2; ++kf) {
      int r = wm * 64 + mf * 16 + lr;
      a2off[mf][kf] = r * 128 + (((kf * 4 + lq) ^ (r & 7)) << 4);
    }
#pragma unroll
  for (int nf = 0; nf < 2; ++nf)
#pragma unroll
    for (int kf = 0; kf < 2; ++kf) {
      int nl = wn * 32 + nf * 16 + lr;
      b2off[nf][kf] = 131072 + nl * 128 + (((kf * 4 + lq) ^ (nl & 7)) << 4);
    }

#define STAGE_W2(s)                                                              \
  { _Pragma("unroll")                                                            \
    for (int i = 0; i < 2; ++i)                                                  \
      gl_lds16(w2 + (size_t)(s) * 16384 + i * 8192 + tid * 16,                   \
               lds + 131072 + ((s) & 1) * 16384 + i * 8192 + tid * 16); }

  STAGE_W2(0); STAGE_W2(1);
  asm volatile("s_waitcnt vmcnt(0)" ::: "memory");
  __builtin_amdgcn_sched_barrier(0);
  __builtin_amdgcn_s_barrier();
  __builtin_amdgcn_sched_barrier(0);

  // ===== phase 2: act @ Wu, 32 steps (8 nt x 4 kc) =====
  f32x4 acc2[4][2];
  for (int s = 0; s < 32; ++s) {
    const int nt = s >> 2, kc = s & 3;
    if (kc == 0) {
#pragma unroll
      for (int mf = 0; mf < 4; ++mf)
#pragma unroll
        for (int nf = 0; nf < 2; ++nf) acc2[mf][nf] = (f32x4){0.f, 0.f, 0.f, 0.f};
    }
    const int bb = (s & 1) * 16384;
#pragma unroll
    for (int kf = 0; kf < 2; ++kf) {
      s16x8 afr[4], bfr[2];
#pragma unroll
      for (int mf = 0; mf < 4; ++mf)
        afr[mf] = *(const s16x8*)(lds + kc * 16384 + a2off[mf][kf]);
#pragma unroll
      for (int nf = 0; nf < 2; ++nf)
        bfr[nf] = *(const s16x8*)(lds + bb + b2off[nf][kf]);
#pragma unroll
      for (int mf = 0; mf < 4; ++mf)
#pragma unroll
        for (int nf = 0; nf < 2; ++nf)
          acc2[mf][nf] = __builtin_amdgcn_mfma_f32_16x16x32_bf16(afr[mf], bfr[nf], acc2[mf][nf], 0, 0, 0);
    }
    asm volatile("s_waitcnt lgkmcnt(0)" ::: "memory");
    __builtin_amdgcn_sched_barrier(0);
    __builtin_amdgcn_s_barrier();
    __builtin_amdgcn_sched_barrier(0);

    if (kc == 3) {
      // epilogue for nt: modulation + asum term + residual, direct stores
#pragma unroll
      for (int mf = 0; mf < 4; ++mf)
#pragma unroll
        for (int j = 0; j < 4; ++j) {
          int r = wm * 64 + mf * 16 + lq * 4 + j;
          size_t base = (size_t)(row0 + r) * 1024 + nt * 128;
          float as = asv[mf][j];
#pragma unroll
          for (int nf = 0; nf < 2; ++nf) {
            size_t gi = base + wn * 32 + nf * 16 + lr;
            out[gi] = acc2[mf][nf][j] * ugA[nt][nf] + ubA[nt][nf] * as + X[gi];
          }
        }
    }
    if (s + 2 < 32) STAGE_W2(s + 2);
    if (s < 31) {
      if (kc == 3 || s >= 30) asm volatile("s_waitcnt vmcnt(0)" ::: "memory");
      else                    asm volatile("s_waitcnt vmcnt(2)" ::: "memory");
      __builtin_amdgcn_sched_barrier(0);
      __builtin_amdgcn_s_barrier();
      __builtin_amdgcn_sched_barrier(0);
    }
  }
}

extern "C" void kernel_launch(void* const* d_in, const int* in_sizes, int n_in,
                              void* d_out, int out_size, void* d_ws, size_t ws_size,
                              hipStream_t stream) {
  const float* hidden       = (const float*)d_in[0];
  const float* conditions   = (const float*)d_in[1];
  const float* down_project = (const float*)d_in[2];
  const float* down_gamma   = (const float*)d_in[3];
  const float* down_beta    = (const float*)d_in[4];
  const float* up_project   = (const float*)d_in[5];
  const float* up_gamma     = (const float*)d_in[6];
  const float* up_beta      = (const float*)d_in[7];
  float* out = (float*)d_out;
  char* ws = (char*)d_ws;

  prep_kernel<<<224, 256, 0, stream>>>(conditions, down_gamma, down_beta, up_gamma, up_beta,
                                       down_project, up_project, ws);
  fused_kernel<<<256, 512, 0, stream>>>(hidden, ws, out);
}